// Round 3
// baseline (120.436 us; speedup 1.0000x reference)
//
#include <hip/hip_runtime.h>
#include <hip/hip_bf16.h>

#define N_NODES 4096
#define N_PER   128
#define D_DIM   64
#define B_GR    32
#define CELLS   (B_GR * N_PER * N_PER)   // 524288 cells, out = cells x 64 f32

// Init: head[cells] = -1 (empty list), cnt[cells] = 0. int4 stores.
__global__ void init_hc(int4* __restrict__ head4, int4* __restrict__ cnt4) {
    int i = blockIdx.x * blockDim.x + threadIdx.x;
    const int HC4 = CELLS / 4;   // 131072
    if (i < HC4)            head4[i] = make_int4(-1, -1, -1, -1);
    else if (i < 2 * HC4)   cnt4[i - HC4] = make_int4(0, 0, 0, 0);
}

// Projection: p1[n][d] = b[d] + sum_k x[n][k]*W[d][k]
//             p2[n][d] =        sum_k x[n][k]*W[d][64+k]
// One wave per node, lane = d.
__global__ void proj_kernel(const float* __restrict__ x,
                            const float* __restrict__ W,
                            const float* __restrict__ b,
                            float* __restrict__ p1,
                            float* __restrict__ p2) {
    int n = blockIdx.x * 4 + (threadIdx.x >> 6);
    int d = threadIdx.x & 63;
    if (n >= N_NODES) return;
    const float* xr = x + (size_t)n * D_DIM;
    const float* w  = W + (size_t)d * (2 * D_DIM);
    float a1 = b[d];
    float a2 = 0.0f;
#pragma unroll
    for (int k = 0; k < D_DIM; ++k) {
        float xv = xr[k];
        a1 += xv * w[k];
        a2 += xv * w[D_DIM + k];
    }
    p1[(size_t)n * D_DIM + d] = a1;
    p2[(size_t)n * D_DIM + d] = a2;
}

// Edges: per-cell linked list via atomicExch (4-B atomics only).
// Tokens: per-cell int count (token value is cell-determined: p1[row]+p2[col]).
__global__ void link_count(const int* __restrict__ esrc,
                           const int* __restrict__ edst,
                           const int* __restrict__ tsrc,
                           const int* __restrict__ tdst,
                           int* __restrict__ head,
                           int* __restrict__ next,
                           int* __restrict__ cnt,
                           int E, int total) {
    int i = blockIdx.x * blockDim.x + threadIdx.x;
    if (i >= total) return;
    if (i < E) {
        int s = esrc[i], t = edst[i];
        int cell = ((s >> 7) << 14) | ((s & 127) << 7) | (t & 127);
        next[i] = atomicExch(&head[cell], i);
    } else {
        int j = i - E;
        int s = tsrc[j], t = tdst[j];
        int cell = ((s >> 7) << 14) | ((s & 127) << 7) | (t & 127);
        atomicAdd(&cnt[cell], 1);
    }
}

// Single-writer combine: out[cell][d] = cnt*(p1[row][d]+p2[col][d]) + sum attr.
// One wave per cell (lane = d), 4 cells per 256-thread block. No atomics.
__global__ void combine(const int* __restrict__ head,
                        const int* __restrict__ next,
                        const int* __restrict__ cnt,
                        const float* __restrict__ attr,
                        const float* __restrict__ p1,
                        const float* __restrict__ p2,
                        float* __restrict__ out) {
    int cell = blockIdx.x * 4 + (threadIdx.x >> 6);
    int d = threadIdx.x & 63;
    int g = cell >> 14;
    int r = (cell >> 7) & 127;
    int c = cell & 127;
    float v = 0.0f;
    int cn = cnt[cell];                      // wave-uniform
    if (cn) {
        v = (float)cn * (p1[(size_t)((g << 7) | r) * D_DIM + d] +
                         p2[(size_t)((g << 7) | c) * D_DIM + d]);
    }
    for (int e = head[cell]; e >= 0; e = next[e])   // avg 0.25 iters
        v += attr[(size_t)e * D_DIM + d];
    out[(size_t)cell * D_DIM + d] = v;
}

extern "C" void kernel_launch(void* const* d_in, const int* in_sizes, int n_in,
                              void* d_out, int out_size, void* d_ws, size_t ws_size,
                              hipStream_t stream) {
    const float* x           = (const float*)d_in[0];
    const int*   edge_index  = (const int*)d_in[1];
    const float* edge_attr   = (const float*)d_in[2];
    // d_in[3] = batch (unused: indices are intra-graph with N_PER=128 stride)
    const int*   token_index = (const int*)d_in[4];
    const float* W           = (const float*)d_in[5];
    const float* b           = (const float*)d_in[6];

    const int E = in_sizes[1] / 2;   // 131072
    const int T = in_sizes[4] / 2;   // 131072

    float* out = (float*)d_out;
    // Workspace layout (all pow2-aligned):
    float* p1   = (float*)d_ws;                      // 4096*64 f32 = 1 MB
    float* p2   = p1 + (size_t)N_NODES * D_DIM;      // 1 MB
    int*   head = (int*)(p2 + (size_t)N_NODES * D_DIM); // 524288 int = 2 MB
    int*   cnt  = head + CELLS;                      // 2 MB
    int*   next = cnt + CELLS;                       // 131072 int = 0.5 MB

    // 1. init head=-1, cnt=0 (4 MB of int4 stores).
    init_hc<<<(2 * CELLS / 4) / 256, 256, 0, stream>>>((int4*)head, (int4*)cnt);

    // 2. projection (independent of init).
    proj_kernel<<<N_NODES / 4, 256, 0, stream>>>(x, W, b, p1, p2);

    // 3. edge linked-lists + token counts (4-B atomics only).
    int total = E + T;
    link_count<<<(total + 255) / 256, 256, 0, stream>>>(
        edge_index, edge_index + E, token_index, token_index + T,
        head, next, cnt, E, total);

    // 4. single-writer combine, no atomics, writes every out element once.
    combine<<<CELLS / 4, 256, 0, stream>>>(head, next, cnt, edge_attr, p1, p2, out);
}

// Round 4
// 70.046 us; speedup vs baseline: 1.7194x; 1.7194x over previous
//
#include <hip/hip_runtime.h>
#include <hip/hip_bf16.h>

#define N_NODES 4096
#define N_PER   128
#define D_DIM   64
#define B_GR    32
#define CELLS   (B_GR * N_PER * N_PER)   // 524288 cells; out = cells x 64 f32

// Fused: blocks [0,1024) init head=-1,cnt=0 (int4 stores);
//        blocks [1024,2048) compute p1/p2 projection (one wave per node).
__global__ void init_proj(int4* __restrict__ head4, int4* __restrict__ cnt4,
                          const float* __restrict__ x,
                          const float* __restrict__ W,
                          const float* __restrict__ b,
                          float* __restrict__ p1,
                          float* __restrict__ p2) {
    if (blockIdx.x < 1024) {
        int i = blockIdx.x * 256 + threadIdx.x;          // 262144 int4 slots
        const int HC4 = CELLS / 4;                       // 131072
        if (i < HC4) head4[i] = make_int4(-1, -1, -1, -1);
        else         cnt4[i - HC4] = make_int4(0, 0, 0, 0);
    } else {
        int n = (blockIdx.x - 1024) * 4 + (threadIdx.x >> 6);
        int d = threadIdx.x & 63;
        const float* xr = x + (size_t)n * D_DIM;
        const float* w  = W + (size_t)d * (2 * D_DIM);
        float a1 = b[d];
        float a2 = 0.0f;
#pragma unroll
        for (int k = 0; k < D_DIM; ++k) {
            float xv = xr[k];
            a1 += xv * w[k];
            a2 += xv * w[D_DIM + k];
        }
        p1[(size_t)n * D_DIM + d] = a1;
        p2[(size_t)n * D_DIM + d] = a2;
    }
}

// Edges: per-cell linked list via atomicExch. Tokens: per-cell int count
// (token contribution is cell-determined: p1[row] + p2[col]).
__global__ void link_count(const int* __restrict__ esrc,
                           const int* __restrict__ edst,
                           const int* __restrict__ tsrc,
                           const int* __restrict__ tdst,
                           int* __restrict__ head,
                           int* __restrict__ next,
                           int* __restrict__ cnt,
                           int E, int total) {
    int i = blockIdx.x * blockDim.x + threadIdx.x;
    if (i >= total) return;
    if (i < E) {
        int s = esrc[i], t = edst[i];
        int cell = ((s >> 7) << 14) | ((s & 127) << 7) | (t & 127);
        next[i] = atomicExch(&head[cell], i);
    } else {
        int j = i - E;
        int s = tsrc[j], t = tdst[j];
        int cell = ((s >> 7) << 14) | ((s & 127) << 7) | (t & 127);
        atomicAdd(&cnt[cell], 1);
    }
}

// BW-structured combine: grid-stride, float4/lane, 16 cells per 256-thread
// block-iteration (lane16 = d-quad, each wave stores 4 cells = 1 KB contig).
// out[cell][:] = cnt[cell]*(p1[cell>>7][:] + p2[colnode][:]) + sum attr[e][:]
__global__ void combine2(const int* __restrict__ head,
                         const int* __restrict__ next,
                         const int* __restrict__ cnt,
                         const float4* __restrict__ attr4,
                         const float4* __restrict__ p14,
                         const float4* __restrict__ p24,
                         float4* __restrict__ out4) {
    const int lane16  = threadIdx.x & 15;        // which float4 of the 64-d row
    const int cellOff = threadIdx.x >> 4;        // 0..15
    for (int base = blockIdx.x * 16; base < CELLS; base += gridDim.x * 16) {
        int cell = base + cellOff;
        int rownode = cell >> 7;                              // (g<<7)|r
        int colnode = ((cell >> 14) << 7) | (cell & 127);     // (g<<7)|c
        float  f  = (float)cnt[cell];                         // 0 for empty
        float4 a  = p14[(size_t)rownode * 16 + lane16];
        float4 b2 = p24[(size_t)colnode * 16 + lane16];
        float4 v;
        v.x = f * (a.x + b2.x);
        v.y = f * (a.y + b2.y);
        v.z = f * (a.z + b2.z);
        v.w = f * (a.w + b2.w);
        for (int e = head[cell]; e >= 0; e = next[e]) {       // avg 0.25 hops
            float4 w = attr4[(size_t)e * 16 + lane16];
            v.x += w.x; v.y += w.y; v.z += w.z; v.w += w.w;
        }
        out4[(size_t)cell * 16 + lane16] = v;
    }
}

extern "C" void kernel_launch(void* const* d_in, const int* in_sizes, int n_in,
                              void* d_out, int out_size, void* d_ws, size_t ws_size,
                              hipStream_t stream) {
    const float* x           = (const float*)d_in[0];
    const int*   edge_index  = (const int*)d_in[1];
    const float* edge_attr   = (const float*)d_in[2];
    // d_in[3] = batch (unused: indices are intra-graph with N_PER=128 stride)
    const int*   token_index = (const int*)d_in[4];
    const float* W           = (const float*)d_in[5];
    const float* b           = (const float*)d_in[6];

    const int E = in_sizes[1] / 2;   // 131072
    const int T = in_sizes[4] / 2;   // 131072

    float* out = (float*)d_out;
    // Workspace layout:
    float* p1   = (float*)d_ws;                         // 4096*64 f32 = 1 MB
    float* p2   = p1 + (size_t)N_NODES * D_DIM;         // 1 MB
    int*   head = (int*)(p2 + (size_t)N_NODES * D_DIM); // 2 MB
    int*   cnt  = head + CELLS;                         // 2 MB
    int*   next = cnt + CELLS;                          // 0.5 MB

    // 1. init head/cnt + projection (independent work, one launch).
    init_proj<<<2048, 256, 0, stream>>>((int4*)head, (int4*)cnt, x, W, b, p1, p2);

    // 2. edge linked-lists + token counts (4-B atomics to L2).
    int total = E + T;
    link_count<<<(total + 255) / 256, 256, 0, stream>>>(
        edge_index, edge_index + E, token_index, token_index + T,
        head, next, cnt, E, total);

    // 3. single-writer streaming combine (no atomics).
    combine2<<<2048, 256, 0, stream>>>(head, next, cnt,
        (const float4*)edge_attr, (const float4*)p1, (const float4*)p2,
        (float4*)out);
}